// Round 1
// baseline (308.212 us; speedup 1.0000x reference)
//
#include <hip/hip_runtime.h>

#define D_F 128   // node feature dim
#define D_H 512   // hidden dim
#define BR  64    // rows per MLP block
#define TB  256   // threads per block
#define CH  64    // hidden-chunk size
#define XS  132   // sX row stride (pad vs 128: breaks same-bank broadcast conflicts)
#define HS  68    // sH row stride (pad vs 64)

// ---------------------------------------------------------------------------
// Init: exclusive cumsum of n_edge -> ec[0..G], node_ids, zero accumulators.
// ---------------------------------------------------------------------------
__global__ __launch_bounds__(256) void init_kernel(
    const int* __restrict__ n_node, const int* __restrict__ n_edge,
    int G, int E,
    int* __restrict__ ec, int* __restrict__ nid,
    float* __restrict__ ew, float* __restrict__ ga)
{
    __shared__ int sne[512];
    __shared__ int snn[512];
    const int t = threadIdx.x;
    for (int g = t; g < G; g += blockDim.x) { sne[g] = n_edge[g]; snn[g] = n_node[g]; }
    __syncthreads();
    for (int g = t; g < G; g += blockDim.x) {
        int se = 0, sn = 0;
        for (int k = 0; k < g; ++k)  se += sne[k];
        for (int k = 0; k <= g; ++k) sn += snn[k];
        ec[g]  = se;
        nid[g] = sn - 1;
        ew[g] = 0.f;
        ga[g] = 0.f;
        if (g == G - 1) {
            int tot = se + sne[g];
            ec[G] = tot > E ? tot : E;   // pad-with-last semantics if sums mismatch
        }
    }
}

// ---------------------------------------------------------------------------
// Fused MLP: h = relu(X @ W1 + b1) @ W2 + b2, 64 rows per block, hidden
// chunked by CH=64 so the 10000x512 intermediate never hits HBM.
// ---------------------------------------------------------------------------
__global__ __launch_bounds__(TB) void mlp_kernel(
    const float* __restrict__ nodes,
    const float* __restrict__ W1, const float* __restrict__ b1,
    const float* __restrict__ W2, const float* __restrict__ b2,
    float* __restrict__ hout, int N)
{
    __shared__ float sX[BR][XS];      // 33.8 KB node tile
    __shared__ float sW1c[D_F][CH];   // 32 KB  W1 column-chunk
    __shared__ float sH[BR][HS];      // 17.4 KB relu(hidden) chunk
    __shared__ float sW2c[CH][D_F];   // 32 KB  W2 row-chunk (contiguous in W2)

    const int t    = threadIdx.x;
    const int r0   = (t >> 4) << 2;   // 4 rows per thread (same in both GEMMs)
    const int c0   = (t & 15) << 2;   // GEMM1: 4 hidden cols per thread
    const int cc0  = (t & 15) << 3;   // GEMM2: 8 out cols per thread
    const int row0 = blockIdx.x * BR;

    float acc2[4][8];
    #pragma unroll
    for (int i = 0; i < 4; ++i)
        #pragma unroll
        for (int j = 0; j < 8; ++j) acc2[i][j] = 0.f;

    // stage node tile (zero-pad tail rows)
    for (int i = t; i < BR * (D_F / 4); i += TB) {
        int r  = i >> 5;
        int c4 = (i & 31) << 2;
        float4 v = {0.f, 0.f, 0.f, 0.f};
        if (row0 + r < N) v = *(const float4*)(nodes + (size_t)(row0 + r) * D_F + c4);
        *(float4*)&sX[r][c4] = v;
    }

    for (int jc = 0; jc < D_H / CH; ++jc) {
        __syncthreads();   // sX staged (iter 0) / previous GEMM2 done reading
        // stage W1[:, jc*CH .. +CH)
        for (int i = t; i < D_F * CH / 4; i += TB) {
            int k  = i >> 4;
            int j4 = (i & 15) << 2;
            *(float4*)&sW1c[k][j4] =
                *(const float4*)(W1 + (size_t)k * D_H + jc * CH + j4);
        }
        // stage W2[jc*CH .. +CH, :]  (contiguous 32 KB)
        const float* W2c = W2 + (size_t)jc * CH * D_F;
        for (int i = t; i < CH * D_F / 4; i += TB) {
            *(float4*)&((float*)sW2c)[i << 2] = *(const float4*)(W2c + (i << 2));
        }
        __syncthreads();

        // GEMM1: hidden chunk (4x4 per thread), K = 128
        float a[4][4];
        #pragma unroll
        for (int i = 0; i < 4; ++i)
            #pragma unroll
            for (int j = 0; j < 4; ++j) a[i][j] = 0.f;

        #pragma unroll 4
        for (int k = 0; k < D_F; ++k) {
            float4 wv = *(const float4*)&sW1c[k][c0];
            float wr[4] = {wv.x, wv.y, wv.z, wv.w};
            float xr[4] = {sX[r0][k], sX[r0 + 1][k], sX[r0 + 2][k], sX[r0 + 3][k]};
            #pragma unroll
            for (int i = 0; i < 4; ++i)
                #pragma unroll
                for (int j = 0; j < 4; ++j)
                    a[i][j] = fmaf(xr[i], wr[j], a[i][j]);
        }
        float4 bb = *(const float4*)(b1 + jc * CH + c0);
        #pragma unroll
        for (int i = 0; i < 4; ++i) {
            float4 v;
            v.x = fmaxf(a[i][0] + bb.x, 0.f);
            v.y = fmaxf(a[i][1] + bb.y, 0.f);
            v.z = fmaxf(a[i][2] + bb.z, 0.f);
            v.w = fmaxf(a[i][3] + bb.w, 0.f);
            *(float4*)&sH[r0 + i][c0] = v;
        }
        __syncthreads();

        // GEMM2: acc2 += relu_chunk @ W2_chunk (4x8 per thread)
        #pragma unroll 2
        for (int kk = 0; kk < CH; ++kk) {
            float4 w0 = *(const float4*)&sW2c[kk][cc0];
            float4 w1 = *(const float4*)&sW2c[kk][cc0 + 4];
            float wr[8] = {w0.x, w0.y, w0.z, w0.w, w1.x, w1.y, w1.z, w1.w};
            float hr[4] = {sH[r0][kk], sH[r0 + 1][kk], sH[r0 + 2][kk], sH[r0 + 3][kk]};
            #pragma unroll
            for (int i = 0; i < 4; ++i)
                #pragma unroll
                for (int j = 0; j < 8; ++j)
                    acc2[i][j] = fmaf(hr[i], wr[j], acc2[i][j]);
        }
    }

    // epilogue: + b2, store h
    float4 b20 = *(const float4*)(b2 + cc0);
    float4 b21 = *(const float4*)(b2 + cc0 + 4);
    #pragma unroll
    for (int i = 0; i < 4; ++i) {
        int r = row0 + r0 + i;
        if (r < N) {
            float4 v0 = {acc2[i][0] + b20.x, acc2[i][1] + b20.y,
                         acc2[i][2] + b20.z, acc2[i][3] + b20.w};
            float4 v1 = {acc2[i][4] + b21.x, acc2[i][5] + b21.y,
                         acc2[i][6] + b21.z, acc2[i][7] + b21.w};
            *(float4*)(hout + (size_t)r * D_F + cc0)     = v0;
            *(float4*)(hout + (size_t)r * D_F + cc0 + 4) = v1;
        }
    }
}

// ---------------------------------------------------------------------------
// Edge stage: 16 lanes per edge; per-group register accumulation per graph,
// flushed with a single atomic pair at graph boundaries.
// ---------------------------------------------------------------------------
__global__ __launch_bounds__(256) void edge_kernel(
    const float* __restrict__ h, const float* __restrict__ wedge,
    const int* __restrict__ senders, const int* __restrict__ receivers,
    const int* __restrict__ ec,
    float* __restrict__ ew, float* __restrict__ ga,
    int E, int G)
{
    const int t       = threadIdx.x;
    const int lane    = t & 15;
    const int gpb     = blockDim.x >> 4;                  // groups per block
    const int group   = blockIdx.x * gpb + (t >> 4);
    const int ngroups = gridDim.x * gpb;
    const int chunk   = (E + ngroups - 1) / ngroups;
    const int e0 = group * chunk;
    const int e1 = min(E, e0 + chunk);
    if (e0 >= e1) return;

    // binary search: largest g with ec[g] <= e0
    int lo = 0, hi = G - 1;
    while (lo < hi) {
        int mid = (lo + hi + 1) >> 1;
        if (ec[mid] <= e0) lo = mid; else hi = mid - 1;
    }
    int gid = lo;
    int ecn = ec[gid + 1];

    float accE = 0.f, accW = 0.f;
    for (int e = e0; e < e1; ++e) {
        if (e >= ecn) {
            if (lane == 0 && (accE != 0.f || accW != 0.f)) {
                atomicAdd(&ga[gid], accE);
                atomicAdd(&ew[gid], accW);
            }
            do { ++gid; ecn = (gid < G) ? ec[gid + 1] : (E + 1); } while (e >= ecn && gid < G - 1);
            accE = 0.f; accW = 0.f;
        }
        int s = senders[e];
        int r = receivers[e];
        float w = wedge[e];
        const float4* hs = (const float4*)(h + (size_t)s * D_F) + (lane << 1);
        const float4* hr = (const float4*)(h + (size_t)r * D_F) + (lane << 1);
        float4 a0 = hs[0], a1 = hs[1];
        float4 c0v = hr[0], c1v = hr[1];
        float dx, part = 0.f;
        dx = a0.x - c0v.x; part += dx * dx;
        dx = a0.y - c0v.y; part += dx * dx;
        dx = a0.z - c0v.z; part += dx * dx;
        dx = a0.w - c0v.w; part += dx * dx;
        dx = a1.x - c1v.x; part += dx * dx;
        dx = a1.y - c1v.y; part += dx * dx;
        dx = a1.z - c1v.z; part += dx * dx;
        dx = a1.w - c1v.w; part += dx * dx;
        part += __shfl_xor(part, 1);
        part += __shfl_xor(part, 2);
        part += __shfl_xor(part, 4);
        part += __shfl_xor(part, 8);
        accE += w * part;   // full 128-dim sum now in every lane of the group
        accW += w;
    }
    if (lane == 0 && (accE != 0.f || accW != 0.f)) {
        atomicAdd(&ga[gid], accE);
        atomicAdd(&ew[gid], accW);
    }
}

// ---------------------------------------------------------------------------
// Finalize: node_out gather + graph_loss mean.
// ---------------------------------------------------------------------------
__global__ __launch_bounds__(256) void finalize_kernel(
    const float* __restrict__ h, const int* __restrict__ nid,
    const float* __restrict__ ew, const float* __restrict__ ga,
    float* __restrict__ out, int G)
{
    const int t = threadIdx.x;
    const int total = G * D_F;
    for (int i = t; i < total; i += blockDim.x) {
        int g = i >> 7;
        int c = i & (D_F - 1);
        out[i] = h[(size_t)nid[g] * D_F + c];
    }
    if (t < 64) {
        float p = 0.f;
        for (int g = t; g < G; g += 64) {
            float w = ew[g];
            p += (w != 0.f) ? ga[g] / w : 0.f;
        }
        #pragma unroll
        for (int m = 32; m > 0; m >>= 1) p += __shfl_xor(p, m);
        if (t == 0) out[total] = p / (float)G;
    }
}

// ---------------------------------------------------------------------------
extern "C" void kernel_launch(void* const* d_in, const int* in_sizes, int n_in,
                              void* d_out, int out_size, void* d_ws, size_t ws_size,
                              hipStream_t stream) {
    const float* nodes     = (const float*)d_in[0];
    const float* edges     = (const float*)d_in[1];
    const int*   senders   = (const int*)d_in[2];
    const int*   receivers = (const int*)d_in[3];
    const int*   n_node    = (const int*)d_in[4];
    const int*   n_edge    = (const int*)d_in[5];
    const float* W1        = (const float*)d_in[6];
    const float* b1        = (const float*)d_in[7];
    const float* W2        = (const float*)d_in[8];
    const float* b2        = (const float*)d_in[9];

    const int N = in_sizes[0] / D_F;
    const int E = in_sizes[1];
    const int G = in_sizes[4];

    float* out = (float*)d_out;

    // workspace layout: h (N*128 f32) | ec (G+1) | nid (G) | ew (G) | ga (G)
    float* h   = (float*)d_ws;
    int*   ec  = (int*)(h + (size_t)N * D_F);
    int*   nid = ec + (G + 1);
    float* ew  = (float*)(nid + G);
    float* ga  = ew + G;

    init_kernel<<<1, 256, 0, stream>>>(n_node, n_edge, G, E, ec, nid, ew, ga);

    const int nblk = (N + BR - 1) / BR;
    mlp_kernel<<<nblk, TB, 0, stream>>>(nodes, W1, b1, W2, b2, h, N);

    edge_kernel<<<1024, 256, 0, stream>>>(h, edges, senders, receivers, ec, ew, ga, E, G);

    finalize_kernel<<<1, 256, 0, stream>>>(h, nid, ew, ga, out, G);
}

// Round 2
// 304.631 us; speedup vs baseline: 1.0118x; 1.0118x over previous
//
#include <hip/hip_runtime.h>

#define D_F 128
#define D_H 512
#define SHS 520   // sH row stride in bf16 elems: 1040 B, 16B-aligned, bank-uniform b128 reads

typedef short v8s __attribute__((ext_vector_type(8)));
typedef float v4f __attribute__((ext_vector_type(4)));

__device__ inline unsigned short f2bf(float f) {
    unsigned u = __float_as_uint(f);
    unsigned r = (u + 0x7fffu + ((u >> 16) & 1u)) >> 16;   // RNE
    return (unsigned short)r;
}
__device__ inline float bf2f(unsigned short s) {
    return __uint_as_float(((unsigned)s) << 16);
}

// ---------------------------------------------------------------------------
// Init: exclusive cumsum of n_edge -> ec[0..G], node_ids, zero accumulators.
// ---------------------------------------------------------------------------
__global__ __launch_bounds__(256) void init_kernel(
    const int* __restrict__ n_node, const int* __restrict__ n_edge,
    int G, int E,
    int* __restrict__ ec, int* __restrict__ nid,
    float* __restrict__ ew, float* __restrict__ ga)
{
    __shared__ int sne[512];
    __shared__ int snn[512];
    const int t = threadIdx.x;
    for (int g = t; g < G; g += blockDim.x) { sne[g] = n_edge[g]; snn[g] = n_node[g]; }
    __syncthreads();
    for (int g = t; g < G; g += blockDim.x) {
        int se = 0, sn = 0;
        for (int k = 0; k < g; ++k)  se += sne[k];
        for (int k = 0; k <= g; ++k) sn += snn[k];
        ec[g]  = se;
        nid[g] = sn - 1;
        ew[g] = 0.f;
        ga[g] = 0.f;
        if (g == G - 1) {
            int tot = se + sne[g];
            ec[G] = tot > E ? tot : E;
        }
    }
}

// ---------------------------------------------------------------------------
// Convert: W1 [128][512] -> W1T bf16 [512][128]; W2 [512][128] -> W2T [128][512]
// ---------------------------------------------------------------------------
__global__ __launch_bounds__(256) void convert_kernel(
    const float* __restrict__ W1, const float* __restrict__ W2,
    unsigned short* __restrict__ W1T, unsigned short* __restrict__ W2T)
{
    int i = blockIdx.x * blockDim.x + threadIdx.x;
    if (i < D_F * D_H) {
        int n = i >> 7, k = i & (D_F - 1);        // W1T[n][k] = W1[k][n]
        W1T[i] = f2bf(W1[k * D_H + n]);
        int n2 = i >> 9, k2 = i & (D_H - 1);      // W2T[n2][k2] = W2[k2][n2]
        W2T[i] = f2bf(W2[k2 * D_F + n2]);
    }
}

// ---------------------------------------------------------------------------
// Fused MLP via MFMA (bf16): 32 rows / block, 2 waves, 16 rows per wave.
// GEMM1: h1 = relu(X @ W1 + b1)  -> bf16 in LDS (A-operand layout source)
// GEMM2: h  = h1 @ W2 + b2       -> hout fp32 + hbf bf16
// ---------------------------------------------------------------------------
__global__ __launch_bounds__(128) void mlp_mfma_kernel(
    const float* __restrict__ nodes,
    const unsigned short* __restrict__ W1T, const float* __restrict__ b1,
    const unsigned short* __restrict__ W2T, const float* __restrict__ b2,
    float* __restrict__ hout, unsigned short* __restrict__ hbf, int N)
{
    __shared__ unsigned short sH[32 * SHS];   // 33.3 KB

    const int t    = threadIdx.x;
    const int wave = t >> 6;
    const int lane = t & 63;
    const int li   = lane & 15;     // m (A) / n (B) / col (C) within 16x16 tile
    const int quad = lane >> 4;     // 0..3
    const int row0 = blockIdx.x * 32 + wave * 16;

    // --- A fragments for GEMM1: X rows, bf16-converted on the fly ----------
    v8s a1[4];
    {
        int r = min(row0 + li, N - 1);
        const float* xp = nodes + (size_t)r * D_F + quad * 8;
        #pragma unroll
        for (int ks = 0; ks < 4; ++ks) {
            float4 f0 = *(const float4*)(xp + ks * 32);
            float4 f1 = *(const float4*)(xp + ks * 32 + 4);
            v8s v;
            v[0] = (short)f2bf(f0.x); v[1] = (short)f2bf(f0.y);
            v[2] = (short)f2bf(f0.z); v[3] = (short)f2bf(f0.w);
            v[4] = (short)f2bf(f1.x); v[5] = (short)f2bf(f1.y);
            v[6] = (short)f2bf(f1.z); v[7] = (short)f2bf(f1.w);
            a1[ks] = v;
        }
    }

    // --- GEMM1: 32 n-tiles of 16 cols, K = 128 (4 MFMA K-steps) ------------
    #pragma unroll 2
    for (int j = 0; j < 32; ++j) {
        const int n0 = j * 16;
        const unsigned short* wp = W1T + (size_t)(n0 + li) * D_F + quad * 8;
        v4f acc = {0.f, 0.f, 0.f, 0.f};
        #pragma unroll
        for (int ks = 0; ks < 4; ++ks) {
            v8s b = *(const v8s*)(wp + ks * 32);
            acc = __builtin_amdgcn_mfma_f32_16x16x32_bf16(a1[ks], b, acc, 0, 0, 0);
        }
        float bias = b1[n0 + li];
        #pragma unroll
        for (int r = 0; r < 4; ++r) {
            float hv = fmaxf(acc[r] + bias, 0.f);
            int m = wave * 16 + quad * 4 + r;       // C layout: row = quad*4+reg
            sH[m * SHS + n0 + li] = f2bf(hv);       // col = li
        }
    }
    __syncthreads();

    // --- A fragments for GEMM2 from LDS (16 K-steps over 512) --------------
    v8s aH[16];
    #pragma unroll
    for (int ks = 0; ks < 16; ++ks) {
        int m  = wave * 16 + li;
        int k0 = ks * 32 + quad * 8;
        aH[ks] = *(const v8s*)(sH + m * SHS + k0);
    }

    // --- GEMM2: 8 n-tiles of 16 output cols, K = 512 -----------------------
    #pragma unroll
    for (int j2 = 0; j2 < 8; ++j2) {
        const int n0 = j2 * 16;
        const unsigned short* wp = W2T + (size_t)(n0 + li) * D_H + quad * 8;
        v4f acc = {0.f, 0.f, 0.f, 0.f};
        #pragma unroll
        for (int ks = 0; ks < 16; ++ks) {
            v8s b = *(const v8s*)(wp + ks * 32);
            acc = __builtin_amdgcn_mfma_f32_16x16x32_bf16(aH[ks], b, acc, 0, 0, 0);
        }
        float bias = b2[n0 + li];
        #pragma unroll
        for (int r = 0; r < 4; ++r) {
            int grow = row0 + quad * 4 + r;
            if (grow < N) {
                float v = acc[r] + bias;
                hout[(size_t)grow * D_F + n0 + li] = v;
                hbf [(size_t)grow * D_F + n0 + li] = f2bf(v);
            }
        }
    }
}

// ---------------------------------------------------------------------------
// Edge stage: 16 lanes/edge on bf16 h (fits per-XCD L2). Branch-free inner
// segments; per-lane accE partials, shuffle-reduced only at segment flush.
// ---------------------------------------------------------------------------
__global__ __launch_bounds__(256) void edge_kernel(
    const unsigned short* __restrict__ hbf, const float* __restrict__ wedge,
    const int* __restrict__ senders, const int* __restrict__ receivers,
    const int* __restrict__ ec,
    float* __restrict__ ew, float* __restrict__ ga,
    int E, int G)
{
    const int t       = threadIdx.x;
    const int lane16  = t & 15;
    const int group   = blockIdx.x * (blockDim.x >> 4) + (t >> 4);
    const int ngroups = gridDim.x * (blockDim.x >> 4);
    const int chunk   = (E + ngroups - 1) / ngroups;
    int e0 = group * chunk;
    int e1 = min(E, e0 + chunk);
    if (e0 >= e1) return;

    // binary search: largest g with ec[g] <= e0
    int lo = 0, hi = G - 1;
    while (lo < hi) {
        int mid = (lo + hi + 1) >> 1;
        if (ec[mid] <= e0) lo = mid; else hi = mid - 1;
    }
    int gid = lo;

    int e = e0;
    while (e < e1) {
        int seg = min(e1, ec[gid + 1]);
        float accE = 0.f, accW = 0.f;
        for (; e < seg; ++e) {                       // branch-free body
            int s = senders[e];
            int r = receivers[e];
            float w = wedge[e];
            v8s hs = *(const v8s*)(hbf + (size_t)s * D_F + lane16 * 8);
            v8s hr = *(const v8s*)(hbf + (size_t)r * D_F + lane16 * 8);
            float part = 0.f;
            #pragma unroll
            for (int u = 0; u < 8; ++u) {
                float d = bf2f((unsigned short)hs[u]) - bf2f((unsigned short)hr[u]);
                part = fmaf(d, d, part);
            }
            accE = fmaf(w, part, accE);              // per-lane partial (8 dims)
            accW += w;
        }
        float red = accE;
        red += __shfl_xor(red, 1);
        red += __shfl_xor(red, 2);
        red += __shfl_xor(red, 4);
        red += __shfl_xor(red, 8);
        if (lane16 == 0 && accW != 0.f) {
            atomicAdd(&ga[gid], red);
            atomicAdd(&ew[gid], accW);
        }
        ++gid;
    }
}

// ---------------------------------------------------------------------------
// Finalize: node_out gather (fp32 h) + graph_loss mean.
// ---------------------------------------------------------------------------
__global__ __launch_bounds__(256) void finalize_kernel(
    const float* __restrict__ h, const int* __restrict__ nid,
    const float* __restrict__ ew, const float* __restrict__ ga,
    float* __restrict__ out, int G)
{
    const int t = threadIdx.x;
    const int total = G * D_F;
    for (int i = t; i < total; i += blockDim.x) {
        int g = i >> 7;
        int c = i & (D_F - 1);
        out[i] = h[(size_t)nid[g] * D_F + c];
    }
    if (t < 64) {
        float p = 0.f;
        for (int g = t; g < G; g += 64) {
            float w = ew[g];
            p += (w != 0.f) ? ga[g] / w : 0.f;
        }
        #pragma unroll
        for (int m = 32; m > 0; m >>= 1) p += __shfl_xor(p, m);
        if (t == 0) out[total] = p / (float)G;
    }
}

// ---------------------------------------------------------------------------
extern "C" void kernel_launch(void* const* d_in, const int* in_sizes, int n_in,
                              void* d_out, int out_size, void* d_ws, size_t ws_size,
                              hipStream_t stream) {
    const float* nodes     = (const float*)d_in[0];
    const float* edges     = (const float*)d_in[1];
    const int*   senders   = (const int*)d_in[2];
    const int*   receivers = (const int*)d_in[3];
    const int*   n_node    = (const int*)d_in[4];
    const int*   n_edge    = (const int*)d_in[5];
    const float* W1        = (const float*)d_in[6];
    const float* b1        = (const float*)d_in[7];
    const float* W2        = (const float*)d_in[8];
    const float* b2        = (const float*)d_in[9];

    const int N = in_sizes[0] / D_F;
    const int E = in_sizes[1];
    const int G = in_sizes[4];

    float* out = (float*)d_out;

    // workspace layout: h fp32 | hbf bf16 | W1T bf16 | W2T bf16 | ec | nid | ew | ga
    float*          h   = (float*)d_ws;
    unsigned short* hbf = (unsigned short*)(h + (size_t)N * D_F);
    unsigned short* W1T = hbf + (size_t)N * D_F;
    unsigned short* W2T = W1T + (size_t)D_F * D_H;
    int*            ec  = (int*)(W2T + (size_t)D_F * D_H);
    int*            nid = ec + (G + 1);
    float*          ew  = (float*)(nid + G);
    float*          ga  = ew + G;

    init_kernel<<<1, 256, 0, stream>>>(n_node, n_edge, G, E, ec, nid, ew, ga);

    convert_kernel<<<(D_F * D_H + 255) / 256, 256, 0, stream>>>(W1, W2, W1T, W2T);

    const int nblk = (N + 31) / 32;
    mlp_mfma_kernel<<<nblk, 128, 0, stream>>>(nodes, W1T, b1, W2T, b2, h, hbf, N);

    edge_kernel<<<2048, 256, 0, stream>>>(hbf, edges, senders, receivers, ec, ew, ga, E, G);

    finalize_kernel<<<1, 256, 0, stream>>>(h, nid, ew, ga, out, G);
}

// Round 3
// 213.663 us; speedup vs baseline: 1.4425x; 1.4258x over previous
//
#include <hip/hip_runtime.h>

#define D_F 128
#define D_H 512
#define SHS 520   // sH row stride (bf16 elems): 1040 B, 16B-aligned

typedef short v8s __attribute__((ext_vector_type(8)));
typedef int   v4i __attribute__((ext_vector_type(4)));
typedef float v4f __attribute__((ext_vector_type(4)));

__device__ inline unsigned short f2bf(float f) {
    unsigned u = __float_as_uint(f);
    unsigned r = (u + 0x7fffu + ((u >> 16) & 1u)) >> 16;   // RNE
    return (unsigned short)r;
}
__device__ inline float bf2f(unsigned short s) {
    return __uint_as_float(((unsigned)s) << 16);
}

// squared distance over 8 bf16 dims packed in 4 dwords
__device__ inline float d2_8(v4i A, v4i B) {
    float acc = 0.f;
    #pragma unroll
    for (int q = 0; q < 4; ++q) {
        unsigned a = (unsigned)A[q], b = (unsigned)B[q];
        float alo = __uint_as_float(a << 16);
        float ahi = __uint_as_float(a & 0xffff0000u);
        float blo = __uint_as_float(b << 16);
        float bhi = __uint_as_float(b & 0xffff0000u);
        float dlo = alo - blo, dhi = ahi - bhi;
        acc = fmaf(dlo, dlo, acc);
        acc = fmaf(dhi, dhi, acc);
    }
    return acc;
}

// ---------------------------------------------------------------------------
// prep: weight conversion (all blocks) + init cumsums/zeros (block 0).
// ---------------------------------------------------------------------------
__global__ __launch_bounds__(256) void prep_kernel(
    const float* __restrict__ W1, const float* __restrict__ W2,
    const int* __restrict__ n_node, const int* __restrict__ n_edge,
    unsigned short* __restrict__ W1T, unsigned short* __restrict__ W2T,
    int* __restrict__ ec, int* __restrict__ nid,
    float* __restrict__ ew, float* __restrict__ ga, int G, int E)
{
    if (blockIdx.x == 0) {
        __shared__ int sne[512];
        __shared__ int snn[512];
        const int t = threadIdx.x;
        for (int g = t; g < G; g += 256) { sne[g] = n_edge[g]; snn[g] = n_node[g]; }
        __syncthreads();
        for (int g = t; g < G; g += 256) {
            int se = 0, sn = 0;
            for (int k = 0; k < g; ++k)  se += sne[k];
            for (int k = 0; k <= g; ++k) sn += snn[k];
            ec[g]  = se;
            nid[g] = sn - 1;
            ew[g] = 0.f;
            ga[g] = 0.f;
            if (g == G - 1) {
                int tot = se + sne[g];
                ec[G] = tot > E ? tot : E;
            }
        }
    }
    int i = blockIdx.x * 256 + threadIdx.x;
    if (i < D_F * D_H) {
        int n = i >> 7, k = i & (D_F - 1);        // W1T[n][k] = W1[k][n]
        W1T[i] = f2bf(W1[k * D_H + n]);
        int n2 = i >> 9, k2 = i & (D_H - 1);      // W2T[n2][k2] = W2[k2][n2]
        W2T[i] = f2bf(W2[k2 * D_F + n2]);
    }
}

// ---------------------------------------------------------------------------
// Fused MLP via MFMA (bf16): 32 rows / block, 2 waves, 16 rows per wave.
// Bounded unrolls (round-2's full unroll of GEMM2 likely spilled to scratch).
// ---------------------------------------------------------------------------
__global__ __launch_bounds__(128) void mlp_mfma_kernel(
    const float* __restrict__ nodes,
    const unsigned short* __restrict__ W1T, const float* __restrict__ b1,
    const unsigned short* __restrict__ W2T, const float* __restrict__ b2,
    unsigned short* __restrict__ hbf, int N)
{
    __shared__ unsigned short sH[32 * SHS];   // 33.3 KB

    const int t    = threadIdx.x;
    const int wave = t >> 6;
    const int lane = t & 63;
    const int li   = lane & 15;
    const int quad = lane >> 4;
    const int row0 = blockIdx.x * 32 + wave * 16;

    // A fragments for GEMM1 (bf16 on the fly)
    v8s a1[4];
    {
        int r = min(row0 + li, N - 1);
        const float* xp = nodes + (size_t)r * D_F + quad * 8;
        #pragma unroll
        for (int ks = 0; ks < 4; ++ks) {
            float4 f0 = *(const float4*)(xp + ks * 32);
            float4 f1 = *(const float4*)(xp + ks * 32 + 4);
            v8s v;
            v[0] = (short)f2bf(f0.x); v[1] = (short)f2bf(f0.y);
            v[2] = (short)f2bf(f0.z); v[3] = (short)f2bf(f0.w);
            v[4] = (short)f2bf(f1.x); v[5] = (short)f2bf(f1.y);
            v[6] = (short)f2bf(f1.z); v[7] = (short)f2bf(f1.w);
            a1[ks] = v;
        }
    }

    // GEMM1: 32 n-tiles of 16 cols, K = 128
    #pragma unroll 2
    for (int j = 0; j < 32; ++j) {
        const int n0 = j * 16;
        const unsigned short* wp = W1T + (size_t)(n0 + li) * D_F + quad * 8;
        v4f acc = {0.f, 0.f, 0.f, 0.f};
        #pragma unroll
        for (int ks = 0; ks < 4; ++ks) {
            v8s b = *(const v8s*)(wp + ks * 32);
            acc = __builtin_amdgcn_mfma_f32_16x16x32_bf16(a1[ks], b, acc, 0, 0, 0);
        }
        float bias = b1[n0 + li];
        #pragma unroll
        for (int r = 0; r < 4; ++r) {
            float hv = fmaxf(acc[r] + bias, 0.f);
            int m = wave * 16 + quad * 4 + r;     // C layout: row = quad*4+reg
            sH[m * SHS + n0 + li] = f2bf(hv);     // col = li
        }
    }
    __syncthreads();

    // A fragments for GEMM2 from LDS
    v8s aH[16];
    #pragma unroll
    for (int ks = 0; ks < 16; ++ks) {
        int m  = wave * 16 + li;
        int k0 = ks * 32 + quad * 8;
        aH[ks] = *(const v8s*)(sH + m * SHS + k0);
    }

    // GEMM2: 8 n-tiles of 16 output cols, K = 512; bounded load batches
    #pragma unroll 1
    for (int j2 = 0; j2 < 8; ++j2) {
        const int n0 = j2 * 16;
        const unsigned short* wp = W2T + (size_t)(n0 + li) * D_H + quad * 8;
        v4f acc = {0.f, 0.f, 0.f, 0.f};
        #pragma unroll
        for (int kc = 0; kc < 4; ++kc) {
            v8s b0 = *(const v8s*)(wp + (kc * 4 + 0) * 32);
            v8s b1v = *(const v8s*)(wp + (kc * 4 + 1) * 32);
            v8s b2v = *(const v8s*)(wp + (kc * 4 + 2) * 32);
            v8s b3v = *(const v8s*)(wp + (kc * 4 + 3) * 32);
            acc = __builtin_amdgcn_mfma_f32_16x16x32_bf16(aH[kc * 4 + 0], b0,  acc, 0, 0, 0);
            acc = __builtin_amdgcn_mfma_f32_16x16x32_bf16(aH[kc * 4 + 1], b1v, acc, 0, 0, 0);
            acc = __builtin_amdgcn_mfma_f32_16x16x32_bf16(aH[kc * 4 + 2], b2v, acc, 0, 0, 0);
            acc = __builtin_amdgcn_mfma_f32_16x16x32_bf16(aH[kc * 4 + 3], b3v, acc, 0, 0, 0);
        }
        float bias = b2[n0 + li];
        #pragma unroll
        for (int r = 0; r < 4; ++r) {
            int grow = row0 + quad * 4 + r;
            if (grow < N)
                hbf[(size_t)grow * D_F + n0 + li] = f2bf(acc[r] + bias);
        }
    }
}

// ---------------------------------------------------------------------------
// Edge stage: 16 lanes/edge, 16-edge tiles. Coalesced nontemporal index
// loads (keep hbf L2-resident), shuffle distribution, 4-edge unroll for MLP.
// ---------------------------------------------------------------------------
__global__ __launch_bounds__(256) void edge_kernel(
    const unsigned short* __restrict__ hbf, const float* __restrict__ wedge,
    const int* __restrict__ senders, const int* __restrict__ receivers,
    const int* __restrict__ ec,
    float* __restrict__ ew, float* __restrict__ ga,
    int E, int G)
{
    __shared__ int sec[513];
    const int t = threadIdx.x;
    for (int i = t; i <= G; i += 256) sec[i] = ec[i];
    __syncthreads();

    const int lane16 = t & 15;
    const int wbase  = t & 48;                    // group base lane in wave
    const int group   = blockIdx.x * 16 + (t >> 4);
    const int ngroups = gridDim.x * 16;
    const int chunk   = (E + ngroups - 1) / ngroups;
    const int e0 = group * chunk;
    const int e1 = min(E, e0 + chunk);
    if (e0 < e1) {
        int gid;
        { int lo = 0, hi = G - 1;
          while (lo < hi) { int m = (lo + hi + 1) >> 1; if (sec[m] <= e0) lo = m; else hi = m - 1; }
          gid = lo; }

        float accE = 0.f, accW = 0.f;

        for (int tb = e0; tb < e1; tb += 16) {
            const int ee  = tb + lane16;
            const bool vld = ee < e1;
            const int ecl = vld ? ee : (e1 - 1);
            int   sv = __builtin_nontemporal_load(senders + ecl);
            int   rv = __builtin_nontemporal_load(receivers + ecl);
            float wv = vld ? __builtin_nontemporal_load(wedge + ecl) : 0.f;
            const int elast = min(tb + 15, e1 - 1);

            if (elast < sec[gid + 1]) {
                // fast path: whole tile in current segment
                #pragma unroll
                for (int i = 0; i < 16; i += 4) {
                    int s0 = __shfl(sv, wbase + i),     r0 = __shfl(rv, wbase + i);
                    int s1 = __shfl(sv, wbase + i + 1), r1 = __shfl(rv, wbase + i + 1);
                    int s2 = __shfl(sv, wbase + i + 2), r2 = __shfl(rv, wbase + i + 2);
                    int s3 = __shfl(sv, wbase + i + 3), r3 = __shfl(rv, wbase + i + 3);
                    v4i A0 = *(const v4i*)(hbf + (size_t)s0 * D_F + lane16 * 8);
                    v4i B0 = *(const v4i*)(hbf + (size_t)r0 * D_F + lane16 * 8);
                    v4i A1 = *(const v4i*)(hbf + (size_t)s1 * D_F + lane16 * 8);
                    v4i B1 = *(const v4i*)(hbf + (size_t)r1 * D_F + lane16 * 8);
                    v4i A2 = *(const v4i*)(hbf + (size_t)s2 * D_F + lane16 * 8);
                    v4i B2 = *(const v4i*)(hbf + (size_t)r2 * D_F + lane16 * 8);
                    v4i A3 = *(const v4i*)(hbf + (size_t)s3 * D_F + lane16 * 8);
                    v4i B3 = *(const v4i*)(hbf + (size_t)r3 * D_F + lane16 * 8);
                    float w0 = __shfl(wv, wbase + i),     w1 = __shfl(wv, wbase + i + 1);
                    float w2 = __shfl(wv, wbase + i + 2), w3 = __shfl(wv, wbase + i + 3);
                    accE = fmaf(w0, d2_8(A0, B0), accE);
                    accE = fmaf(w1, d2_8(A1, B1), accE);
                    accE = fmaf(w2, d2_8(A2, B2), accE);
                    accE = fmaf(w3, d2_8(A3, B3), accE);
                }
                accW += wv;   // own (masked) weight; lane-sum = tile sum
            } else {
                // boundary tile: per-edge with segment flushes
                for (int i = 0; i < 16; ++i) {
                    int eea = tb + i;
                    if (eea >= e1) break;
                    while (eea >= sec[gid + 1]) {
                        float rE = accE, rW = accW;
                        rE += __shfl_xor(rE, 1); rW += __shfl_xor(rW, 1);
                        rE += __shfl_xor(rE, 2); rW += __shfl_xor(rW, 2);
                        rE += __shfl_xor(rE, 4); rW += __shfl_xor(rW, 4);
                        rE += __shfl_xor(rE, 8); rW += __shfl_xor(rW, 8);
                        if (lane16 == 0 && (rE != 0.f || rW != 0.f)) {
                            atomicAdd(&ga[gid], rE);
                            atomicAdd(&ew[gid], rW);
                        }
                        accE = 0.f; accW = 0.f;
                        ++gid;
                    }
                    int s = __shfl(sv, wbase + i), r = __shfl(rv, wbase + i);
                    float w = __shfl(wv, wbase + i);
                    v4i A = *(const v4i*)(hbf + (size_t)s * D_F + lane16 * 8);
                    v4i B = *(const v4i*)(hbf + (size_t)r * D_F + lane16 * 8);
                    accE = fmaf(w, d2_8(A, B), accE);
                    if (lane16 == 0) accW += w;   // single-lane: lane-sum = tile sum
                }
            }
        }
        // final flush
        float rE = accE, rW = accW;
        rE += __shfl_xor(rE, 1); rW += __shfl_xor(rW, 1);
        rE += __shfl_xor(rE, 2); rW += __shfl_xor(rW, 2);
        rE += __shfl_xor(rE, 4); rW += __shfl_xor(rW, 4);
        rE += __shfl_xor(rE, 8); rW += __shfl_xor(rW, 8);
        if (lane16 == 0 && (rE != 0.f || rW != 0.f)) {
            atomicAdd(&ga[gid], rE);
            atomicAdd(&ew[gid], rW);
        }
    }
}

// ---------------------------------------------------------------------------
// Finalize: block g < G gathers node_out row; block G computes loss.
// ---------------------------------------------------------------------------
__global__ __launch_bounds__(128) void finalize_kernel(
    const unsigned short* __restrict__ hbf, const int* __restrict__ nid,
    const float* __restrict__ ew, const float* __restrict__ ga,
    float* __restrict__ out, int G)
{
    const int g = blockIdx.x;
    const int t = threadIdx.x;
    if (g < G) {
        int src = nid[g];
        out[(size_t)g * D_F + t] = bf2f(hbf[(size_t)src * D_F + t]);
    } else {
        float p = 0.f;
        for (int i = t; i < G; i += 128) {
            float w = ew[i];
            p += (w != 0.f) ? ga[i] / w : 0.f;
        }
        #pragma unroll
        for (int m = 32; m > 0; m >>= 1) p += __shfl_xor(p, m);
        __shared__ float sp[2];
        if ((t & 63) == 0) sp[t >> 6] = p;
        __syncthreads();
        if (t == 0) out[(size_t)G * D_F] = (sp[0] + sp[1]) / (float)G;
    }
}

// ---------------------------------------------------------------------------
extern "C" void kernel_launch(void* const* d_in, const int* in_sizes, int n_in,
                              void* d_out, int out_size, void* d_ws, size_t ws_size,
                              hipStream_t stream) {
    const float* nodes     = (const float*)d_in[0];
    const float* edges     = (const float*)d_in[1];
    const int*   senders   = (const int*)d_in[2];
    const int*   receivers = (const int*)d_in[3];
    const int*   n_node    = (const int*)d_in[4];
    const int*   n_edge    = (const int*)d_in[5];
    const float* W1        = (const float*)d_in[6];
    const float* b1        = (const float*)d_in[7];
    const float* W2        = (const float*)d_in[8];
    const float* b2        = (const float*)d_in[9];

    const int N = in_sizes[0] / D_F;
    const int E = in_sizes[1];
    const int G = in_sizes[4];

    float* out = (float*)d_out;

    // workspace: hbf bf16 | W1T bf16 | W2T bf16 | ec | nid | ew | ga
    unsigned short* hbf = (unsigned short*)d_ws;
    unsigned short* W1T = hbf + (size_t)N * D_F;
    unsigned short* W2T = W1T + (size_t)D_F * D_H;
    int*            ec  = (int*)(W2T + (size_t)D_F * D_H);
    int*            nid = ec + (G + 1);
    float*          ew  = (float*)(nid + G);
    float*          ga  = ew + G;

    prep_kernel<<<(D_F * D_H + 255) / 256, 256, 0, stream>>>(
        W1, W2, n_node, n_edge, W1T, W2T, ec, nid, ew, ga, G, E);

    const int nblk = (N + 31) / 32;
    mlp_mfma_kernel<<<nblk, 128, 0, stream>>>(nodes, W1T, b1, W2T, b2, hbf, N);

    edge_kernel<<<1024, 256, 0, stream>>>(hbf, edges, senders, receivers, ec, ew, ga, E, G);

    finalize_kernel<<<G + 1, 128, 0, stream>>>(hbf, nid, ew, ga, out, G);
}

// Round 4
// 160.359 us; speedup vs baseline: 1.9220x; 1.3324x over previous
//
#include <hip/hip_runtime.h>

#define D_F 128
#define D_H 512
#define SHS 520   // sH row stride (bf16 elems): 1040 B, 16B-aligned

typedef short v8s __attribute__((ext_vector_type(8)));
typedef float v4f __attribute__((ext_vector_type(4)));

__device__ inline unsigned short f2bf(float f) {
    unsigned u = __float_as_uint(f);
    unsigned r = (u + 0x7fffu + ((u >> 16) & 1u)) >> 16;   // RNE
    return (unsigned short)r;
}
__device__ inline float bf2f(unsigned short s) {
    return __uint_as_float(((unsigned)s) << 16);
}

// ---------------------------------------------------------------------------
// prep: weight conversion (all blocks) + init cumsums/zeros (block 0).
// ---------------------------------------------------------------------------
__global__ __launch_bounds__(256) void prep_kernel(
    const float* __restrict__ W1, const float* __restrict__ W2,
    const int* __restrict__ n_node, const int* __restrict__ n_edge,
    unsigned short* __restrict__ W1T, unsigned short* __restrict__ W2T,
    int* __restrict__ ec, int* __restrict__ nid,
    float* __restrict__ ew, float* __restrict__ ga, int G, int E)
{
    if (blockIdx.x == 0) {
        __shared__ int sne[512];
        __shared__ int snn[512];
        const int t = threadIdx.x;
        for (int g = t; g < G; g += 256) { sne[g] = n_edge[g]; snn[g] = n_node[g]; }
        __syncthreads();
        for (int g = t; g < G; g += 256) {
            int se = 0, sn = 0;
            for (int k = 0; k < g; ++k)  se += sne[k];
            for (int k = 0; k <= g; ++k) sn += snn[k];
            ec[g]  = se;
            nid[g] = sn - 1;
            ew[g] = 0.f;
            ga[g] = 0.f;
            if (g == G - 1) {
                int tot = se + sne[g];
                ec[G] = tot > E ? tot : E;
            }
        }
    }
    int i = blockIdx.x * 256 + threadIdx.x;
    if (i < D_F * D_H) {
        int n = i >> 7, k = i & (D_F - 1);        // W1T[n][k] = W1[k][n]
        W1T[i] = f2bf(W1[k * D_H + n]);
        int n2 = i >> 9, k2 = i & (D_H - 1);      // W2T[n2][k2] = W2[k2][n2]
        W2T[i] = f2bf(W2[k2 * D_F + n2]);
    }
}

// ---------------------------------------------------------------------------
// Fused MLP via MFMA (bf16): 16 rows / block, 4 waves splitting the
// n-dimension (2500 waves total vs 625 before -> 4x latency hiding).
// ---------------------------------------------------------------------------
__global__ __launch_bounds__(256) void mlp_mfma_kernel(
    const float* __restrict__ nodes,
    const unsigned short* __restrict__ W1T, const float* __restrict__ b1,
    const unsigned short* __restrict__ W2T, const float* __restrict__ b2,
    unsigned short* __restrict__ hbf, int N)
{
    __shared__ unsigned short sH[16 * SHS];   // 16.6 KB

    const int t    = threadIdx.x;
    const int wave = t >> 6;
    const int lane = t & 63;
    const int li   = lane & 15;
    const int quad = lane >> 4;
    const int row0 = blockIdx.x * 16;

    // A fragments for GEMM1 (same 16 rows for all 4 waves; L1-served)
    v8s a1[4];
    {
        int r = min(row0 + li, N - 1);
        const float* xp = nodes + (size_t)r * D_F + quad * 8;
        #pragma unroll
        for (int ks = 0; ks < 4; ++ks) {
            float4 f0 = *(const float4*)(xp + ks * 32);
            float4 f1 = *(const float4*)(xp + ks * 32 + 4);
            v8s v;
            v[0] = (short)f2bf(f0.x); v[1] = (short)f2bf(f0.y);
            v[2] = (short)f2bf(f0.z); v[3] = (short)f2bf(f0.w);
            v[4] = (short)f2bf(f1.x); v[5] = (short)f2bf(f1.y);
            v[6] = (short)f2bf(f1.z); v[7] = (short)f2bf(f1.w);
            a1[ks] = v;
        }
    }

    // GEMM1: this wave covers hidden cols [wave*128, wave*128+128)
    #pragma unroll 2
    for (int jj = 0; jj < 8; ++jj) {
        const int n0 = (wave * 8 + jj) * 16;
        const unsigned short* wp = W1T + (size_t)(n0 + li) * D_F + quad * 8;
        v4f acc = {0.f, 0.f, 0.f, 0.f};
        #pragma unroll
        for (int ks = 0; ks < 4; ++ks) {
            v8s b = *(const v8s*)(wp + ks * 32);
            acc = __builtin_amdgcn_mfma_f32_16x16x32_bf16(a1[ks], b, acc, 0, 0, 0);
        }
        float bias = b1[n0 + li];
        #pragma unroll
        for (int r = 0; r < 4; ++r) {
            float hv = fmaxf(acc[r] + bias, 0.f);
            int m = quad * 4 + r;                 // C layout: row = quad*4+reg
            sH[m * SHS + n0 + li] = f2bf(hv);     // col = li
        }
    }
    __syncthreads();

    // A fragments for GEMM2 from LDS
    v8s aH[16];
    #pragma unroll
    for (int ks = 0; ks < 16; ++ks)
        aH[ks] = *(const v8s*)(sH + li * SHS + ks * 32 + quad * 8);

    // GEMM2: this wave covers output cols [wave*32, wave*32+32)
    #pragma unroll 1
    for (int j2 = 0; j2 < 2; ++j2) {
        const int n0 = (wave * 2 + j2) * 16;
        const unsigned short* wp = W2T + (size_t)(n0 + li) * D_H + quad * 8;
        v4f acc = {0.f, 0.f, 0.f, 0.f};
        #pragma unroll
        for (int kc = 0; kc < 4; ++kc) {
            v8s b0 = *(const v8s*)(wp + (kc * 4 + 0) * 32);
            v8s b1v = *(const v8s*)(wp + (kc * 4 + 1) * 32);
            v8s b2v = *(const v8s*)(wp + (kc * 4 + 2) * 32);
            v8s b3v = *(const v8s*)(wp + (kc * 4 + 3) * 32);
            acc = __builtin_amdgcn_mfma_f32_16x16x32_bf16(aH[kc * 4 + 0], b0,  acc, 0, 0, 0);
            acc = __builtin_amdgcn_mfma_f32_16x16x32_bf16(aH[kc * 4 + 1], b1v, acc, 0, 0, 0);
            acc = __builtin_amdgcn_mfma_f32_16x16x32_bf16(aH[kc * 4 + 2], b2v, acc, 0, 0, 0);
            acc = __builtin_amdgcn_mfma_f32_16x16x32_bf16(aH[kc * 4 + 3], b3v, acc, 0, 0, 0);
        }
        float bias = b2[n0 + li];
        #pragma unroll
        for (int r = 0; r < 4; ++r) {
            int grow = row0 + quad * 4 + r;
            if (grow < N)
                hbf[(size_t)grow * D_F + n0 + li] = f2bf(acc[r] + bias);
        }
    }
}

// ---------------------------------------------------------------------------
// Edge stage: one WAVE per edge stream; all 64 lanes cooperate on each edge.
// Lane l owns dims {2l, 2l+1}: loads one dword of src row + one of dst row
// (fully coalesced 256 B per row). Per-lane accumulation across edges;
// 64-lane reduce only at segment flush. LDS-staged per-block atomics.
// ---------------------------------------------------------------------------
__global__ __launch_bounds__(256) void edge_kernel(
    const unsigned short* __restrict__ hbf, const float* __restrict__ wedge,
    const int* __restrict__ senders, const int* __restrict__ receivers,
    const int* __restrict__ ec,
    float* __restrict__ ew, float* __restrict__ ga,
    int E, int G)
{
    __shared__ int   sec[513];
    __shared__ float sga[512];
    __shared__ float sew[512];
    const int t = threadIdx.x;
    for (int i = t; i <= G; i += 256) sec[i] = ec[i];
    for (int i = t; i < G;  i += 256) { sga[i] = 0.f; sew[i] = 0.f; }
    __syncthreads();

    const unsigned* __restrict__ h32 = (const unsigned*)hbf;   // row = 64 dwords
    const int lane   = t & 63;
    const int wid    = blockIdx.x * 4 + (t >> 6);
    const int nwaves = gridDim.x * 4;
    const int chunk  = (E + nwaves - 1) / nwaves;
    const int e0 = wid * chunk;
    const int e1 = min(E, e0 + chunk);

    if (e0 < e1) {
        int gid;
        { int lo = 0, hi = G - 1;
          while (lo < hi) { int m = (lo + hi + 1) >> 1; if (sec[m] <= e0) lo = m; else hi = m - 1; }
          gid = lo; }

        float accE = 0.f, accW = 0.f;   // accW is lane-uniform by construction

        for (int tb = e0; tb < e1; tb += 64) {
            const int nt  = min(64, e1 - tb);
            const int ecl = min(tb + lane, e1 - 1);
            const bool vld = (tb + lane) < e1;
            int   sv = __builtin_nontemporal_load(senders + ecl);
            int   rv = __builtin_nontemporal_load(receivers + ecl);
            float wv = vld ? __builtin_nontemporal_load(wedge + ecl) : 0.f;

            if (tb + nt <= sec[gid + 1]) {
                // fast path: all valid edges of this tile in current segment.
                // clamped tail edges have w=0 -> harmless to process.
                #pragma unroll 1
                for (int i = 0; i < 64; i += 8) {
                    unsigned av[8], bv[8];
                    int su[8], ru[8];
                    #pragma unroll
                    for (int u = 0; u < 8; ++u) {
                        su[u] = __shfl(sv, i + u);
                        ru[u] = __shfl(rv, i + u);
                    }
                    #pragma unroll
                    for (int u = 0; u < 8; ++u) {
                        av[u] = h32[(size_t)su[u] * 64 + lane];
                        bv[u] = h32[(size_t)ru[u] * 64 + lane];
                    }
                    #pragma unroll
                    for (int u = 0; u < 8; ++u) {
                        float w = __shfl(wv, i + u);
                        float alo = __uint_as_float(av[u] << 16);
                        float ahi = __uint_as_float(av[u] & 0xffff0000u);
                        float blo = __uint_as_float(bv[u] << 16);
                        float bhi = __uint_as_float(bv[u] & 0xffff0000u);
                        float dlo = alo - blo, dhi = ahi - bhi;
                        float sq  = fmaf(dlo, dlo, dhi * dhi);
                        accE = fmaf(w, sq, accE);
                        accW += w;
                    }
                }
            } else {
                // boundary tile: per-edge with segment flushes
                for (int i = 0; i < nt; ++i) {
                    int e = tb + i;
                    while (e >= sec[gid + 1]) {
                        float rE = accE;
                        #pragma unroll
                        for (int m = 32; m > 0; m >>= 1) rE += __shfl_xor(rE, m);
                        if (lane == 0 && (rE != 0.f || accW != 0.f)) {
                            atomicAdd(&sga[gid], rE);
                            atomicAdd(&sew[gid], accW);
                        }
                        accE = 0.f; accW = 0.f;
                        ++gid;
                    }
                    int   s = __shfl(sv, i);
                    int   r = __shfl(rv, i);
                    float w = __shfl(wv, i);
                    unsigned a = h32[(size_t)s * 64 + lane];
                    unsigned b = h32[(size_t)r * 64 + lane];
                    float alo = __uint_as_float(a << 16);
                    float ahi = __uint_as_float(a & 0xffff0000u);
                    float blo = __uint_as_float(b << 16);
                    float bhi = __uint_as_float(b & 0xffff0000u);
                    float dlo = alo - blo, dhi = ahi - bhi;
                    float sq  = fmaf(dlo, dlo, dhi * dhi);
                    accE = fmaf(w, sq, accE);
                    accW += w;
                }
            }
        }
        // final flush
        float rE = accE;
        #pragma unroll
        for (int m = 32; m > 0; m >>= 1) rE += __shfl_xor(rE, m);
        if (lane == 0 && (rE != 0.f || accW != 0.f)) {
            atomicAdd(&sga[gid], rE);
            atomicAdd(&sew[gid], accW);
        }
    }

    __syncthreads();
    for (int g = t; g < G; g += 256) {
        float vg = sga[g], vw = sew[g];
        if (vg != 0.f || vw != 0.f) {
            atomicAdd(&ga[g], vg);
            atomicAdd(&ew[g], vw);
        }
    }
}

// ---------------------------------------------------------------------------
// Finalize: block g < G gathers node_out row; block G computes loss.
// ---------------------------------------------------------------------------
__global__ __launch_bounds__(128) void finalize_kernel(
    const unsigned short* __restrict__ hbf, const int* __restrict__ nid,
    const float* __restrict__ ew, const float* __restrict__ ga,
    float* __restrict__ out, int G)
{
    const int g = blockIdx.x;
    const int t = threadIdx.x;
    if (g < G) {
        int src = nid[g];
        out[(size_t)g * D_F + t] = bf2f(hbf[(size_t)src * D_F + t]);
    } else {
        float p = 0.f;
        for (int i = t; i < G; i += 128) {
            float w = ew[i];
            p += (w != 0.f) ? ga[i] / w : 0.f;
        }
        #pragma unroll
        for (int m = 32; m > 0; m >>= 1) p += __shfl_xor(p, m);
        __shared__ float sp[2];
        if ((t & 63) == 0) sp[t >> 6] = p;
        __syncthreads();
        if (t == 0) out[(size_t)G * D_F] = (sp[0] + sp[1]) / (float)G;
    }
}

// ---------------------------------------------------------------------------
extern "C" void kernel_launch(void* const* d_in, const int* in_sizes, int n_in,
                              void* d_out, int out_size, void* d_ws, size_t ws_size,
                              hipStream_t stream) {
    const float* nodes     = (const float*)d_in[0];
    const float* edges     = (const float*)d_in[1];
    const int*   senders   = (const int*)d_in[2];
    const int*   receivers = (const int*)d_in[3];
    const int*   n_node    = (const int*)d_in[4];
    const int*   n_edge    = (const int*)d_in[5];
    const float* W1        = (const float*)d_in[6];
    const float* b1        = (const float*)d_in[7];
    const float* W2        = (const float*)d_in[8];
    const float* b2        = (const float*)d_in[9];

    const int N = in_sizes[0] / D_F;
    const int E = in_sizes[1];
    const int G = in_sizes[4];

    float* out = (float*)d_out;

    // workspace: hbf bf16 | W1T bf16 | W2T bf16 | ec | nid | ew | ga
    unsigned short* hbf = (unsigned short*)d_ws;
    unsigned short* W1T = hbf + (size_t)N * D_F;
    unsigned short* W2T = W1T + (size_t)D_F * D_H;
    int*            ec  = (int*)(W2T + (size_t)D_F * D_H);
    int*            nid = ec + (G + 1);
    float*          ew  = (float*)(nid + G);
    float*          ga  = ew + G;

    prep_kernel<<<(D_F * D_H + 255) / 256, 256, 0, stream>>>(
        W1, W2, n_node, n_edge, W1T, W2T, ec, nid, ew, ga, G, E);

    const int nblk = (N + 15) / 16;
    mlp_mfma_kernel<<<nblk, 256, 0, stream>>>(nodes, W1T, b1, W2T, b2, hbf, N);

    edge_kernel<<<2048, 256, 0, stream>>>(hbf, edges, senders, receivers, ec, ew, ga, E, G);

    finalize_kernel<<<G + 1, 128, 0, stream>>>(hbf, nid, ew, ga, out, G);
}